// Round 1
// baseline (1972.570 us; speedup 1.0000x reference)
//
#include <hip/hip_runtime.h>
#include <stdint.h>

// ---------------------------------------------------------------------------
// Node_GCN: PAE edge weights (MLP+BN+dropout+cosine) -> 2x GCNConv -> MLP head
// All fp32. Correctness round: exact JAX threefry2x32 PRNG replication
// (partitionable mode, JAX >= 0.4.36 default). Flip JAX_PARTITIONABLE to 0 to
// get the legacy (pre-0.4.36) construction.
// Workspace layout (floats): [bn_sums 512][bn_ab 512][EW 1e6][DINV 1e5]
//                            [BUFA 6.4e6][BUFB 6.4e6]  = 55.6 MB total.
// ---------------------------------------------------------------------------

#define JAX_PARTITIONABLE 1

#define NN 100000
#define NE 1000000
#define INV_KEEP (1.0f/0.7f)

__device__ __forceinline__ uint32_t rotl32(uint32_t x, int r) {
  return (x << r) | (x >> (32 - r));
}

// Threefry-2x32, 20 rounds, exactly as in jax/_src/prng.py
__device__ __forceinline__ void threefry2x32(uint32_t k0, uint32_t k1,
                                             uint32_t x0, uint32_t x1,
                                             uint32_t& o0, uint32_t& o1) {
  uint32_t k2 = k0 ^ k1 ^ 0x1BD11BDAu;
  x0 += k0; x1 += k1;
#define TF_R(r) { x0 += x1; x1 = rotl32(x1, (r)); x1 ^= x0; }
  TF_R(13) TF_R(15) TF_R(26) TF_R(6)   x0 += k1; x1 += k2 + 1u;
  TF_R(17) TF_R(29) TF_R(16) TF_R(24)  x0 += k2; x1 += k0 + 2u;
  TF_R(13) TF_R(15) TF_R(26) TF_R(6)   x0 += k0; x1 += k1 + 3u;
  TF_R(17) TF_R(29) TF_R(16) TF_R(24)  x0 += k1; x1 += k2 + 4u;
  TF_R(13) TF_R(15) TF_R(26) TF_R(6)   x0 += k2; x1 += k0 + 5u;
#undef TF_R
  o0 = x0; o1 = x1;
}

// keys from jax.random.split(jax.random.key(42))
__device__ __forceinline__ void jax_split42(uint32_t& kp0, uint32_t& kp1,
                                            uint32_t& kh0, uint32_t& kh1) {
#if JAX_PARTITIONABLE
  threefry2x32(0u, 42u, 0u, 0u, kp0, kp1);
  threefry2x32(0u, 42u, 0u, 1u, kh0, kh1);
#else
  uint32_t a0, a1, b0, b1;
  threefry2x32(0u, 42u, 0u, 2u, a0, a1);
  threefry2x32(0u, 42u, 1u, 3u, b0, b1);
  kp0 = a0; kp1 = b0; kh0 = a1; kh1 = b1;
#endif
}

#if JAX_PARTITIONABLE
__device__ __forceinline__ uint32_t tf_bits32(uint32_t k0, uint32_t k1, uint32_t idx) {
  uint32_t o0, o1;
  threefry2x32(k0, k1, 0u, idx, o0, o1);
  return o0 ^ o1;
}
#endif

// jax.random.uniform(bits) < 0.7  (keep probability)
__device__ __forceinline__ bool bits_keep(uint32_t bits) {
  float u = __uint_as_float((bits >> 9) | 0x3F800000u) - 1.0f;
  return u < 0.7f;
}

// ---------------------------------------------------------------------------
// K1: BN statistics. sums[0..255] = sum h, sums[256..511] = sum h^2, t=(s,c).
// ---------------------------------------------------------------------------
__global__ __launch_bounds__(256) void bn_stats(const float* __restrict__ edgenet,
                                                const float* __restrict__ w1,
                                                const float* __restrict__ b1,
                                                float* __restrict__ sums) {
  __shared__ float w1s[256];
  __shared__ float b1s[128];
  __shared__ float ed[256];
  int t = threadIdx.x;
  if (t < 128) { w1s[t] = w1[t]; w1s[128 + t] = w1[128 + t]; b1s[t] = b1[t]; }
  __syncthreads();
  int s = t >> 7, c = t & 127;
  float wA = w1s[c], wB = w1s[128 + c], bb = b1s[c];
  const int per = (NE + gridDim.x - 1) / gridDim.x;
  int e_beg = blockIdx.x * per;
  int e_end = min(e_beg + per, NE);
  float sum = 0.f, sq = 0.f;
  for (int eb = e_beg; eb < e_end; eb += 64) {
    int n = min(64, e_end - eb);
    __syncthreads();
    if (t < n * 4) ed[t] = edgenet[eb * 4 + t];
    __syncthreads();
    for (int i = 0; i < n; ++i) {
      float x0 = ed[i * 4 + 2 * s], x1 = ed[i * 4 + 2 * s + 1];
      float h = fmaf(x1, wB, fmaf(x0, wA, bb));
      h = fmaxf(h, 0.f);
      sum += h;
      sq = fmaf(h, h, sq);
    }
  }
  atomicAdd(&sums[t], sum);
  atomicAdd(&sums[256 + t], sq);
}

// ---------------------------------------------------------------------------
// K2: BN finalize -> affine (a,b): hn = h*a + b.   ab[0..255]=a, ab[256..511]=b
// ---------------------------------------------------------------------------
__global__ void bn_finalize(const float* __restrict__ sums,
                            const float* __restrict__ gamma,
                            const float* __restrict__ beta,
                            float* __restrict__ ab) {
  int t = threadIdx.x;  // 256
  int c = t & 127;
  const float invE = 1.0f / (float)NE;
  float mean = sums[t] * invE;
  float var = fmaxf(sums[256 + t] * invE - mean * mean, 0.f);
  float rstd = rsqrtf(var + 1e-5f);
  float a = gamma[c] * rstd;
  ab[t] = a;
  ab[256 + t] = beta[c] - mean * a;
}

// ---------------------------------------------------------------------------
// K3: PAE fused: h1 = relu(x@w1+b1), BN-affine, dropout, h2 = hd@w2+b2,
// cosine -> edge weight. 32 edges/block, rows r=2*el+s (64), couts 128.
// hd^T tile in LDS (stride 68), w2 streamed from global (L2-resident 64KB).
// Thread (ty,tx): 4 rows x 8 couts register tile.
// ---------------------------------------------------------------------------
__global__ __launch_bounds__(256) void pae_edge(const float* __restrict__ edgenet,
                                                const float* __restrict__ w1,
                                                const float* __restrict__ b1,
                                                const float* __restrict__ ab,
                                                const float* __restrict__ w2,
                                                const float* __restrict__ b2,
                                                float* __restrict__ ew_out) {
  __shared__ __align__(16) float hdt[128 * 68];
  __shared__ float4 ed4[32];
  __shared__ float w1s[256], b1s[128], aS[256], bS[256], b2s[128];
  int t = threadIdx.x;
  int e0 = blockIdx.x * 32;
  if (t < 128) { w1s[t] = w1[t]; w1s[128 + t] = w1[128 + t]; b1s[t] = b1[t]; b2s[t] = b2[t]; }
  aS[t] = ab[t];
  bS[t] = ab[256 + t];
  if (t < 32) ed4[t] = ((const float4*)edgenet)[e0 + t];

  uint32_t kp0, kp1, kh0, kh1;
  jax_split42(kp0, kp1, kh0, kh1);
  __syncthreads();

  // staging: compute dropout-applied normalized h1 into hdt[k][row]
  for (int it = 0; it < 16; ++it) {
    int idx = it * 256 + t;        // [0, 4096)
    int el = idx & 31;             // edge within block
    int c = idx >> 5;              // channel [0,128)
    float4 xv = ed4[el];
    float wA = w1s[c], wB = w1s[128 + c], bb = b1s[c];
    float h0 = fmaxf(fmaf(xv.y, wB, fmaf(xv.x, wA, bb)), 0.f);   // s=0
    float h1 = fmaxf(fmaf(xv.w, wB, fmaf(xv.z, wA, bb)), 0.f);   // s=1
    float hn0 = fmaf(h0, aS[c], bS[c]);
    float hn1 = fmaf(h1, aS[128 + c], bS[128 + c]);
    uint32_t base = (uint32_t)((e0 + el) * 128 + c);
#if JAX_PARTITIONABLE
    bool keep0 = bits_keep(tf_bits32(kp0, kp1, base));
    bool keep1 = bits_keep(tf_bits32(kp0, kp1, base + 128000000u));
#else
    uint32_t o0, o1;
    threefry2x32(kp0, kp1, base, base + 128000000u, o0, o1);
    bool keep0 = bits_keep(o0);
    bool keep1 = bits_keep(o1);
#endif
    float hd0 = keep0 ? hn0 * INV_KEEP : 0.f;
    float hd1 = keep1 ? hn1 * INV_KEEP : 0.f;
    ((float2*)(hdt + c * 68))[el] = make_float2(hd0, hd1);
  }
  __syncthreads();

  int tx = t & 15, ty = t >> 4;
  float acc[4][8];
#pragma unroll
  for (int i = 0; i < 4; ++i)
#pragma unroll
    for (int j = 0; j < 8; ++j) acc[i][j] = 0.f;

  const float4* w2v = (const float4*)w2;
#pragma unroll 4
  for (int k = 0; k < 128; ++k) {
    float4 av = *(const float4*)&hdt[k * 68 + 4 * ty];
    float4 b0 = w2v[k * 32 + 2 * tx];
    float4 b1v = w2v[k * 32 + 2 * tx + 1];
    float a4[4] = {av.x, av.y, av.z, av.w};
    float b8[8] = {b0.x, b0.y, b0.z, b0.w, b1v.x, b1v.y, b1v.z, b1v.w};
#pragma unroll
    for (int i = 0; i < 4; ++i)
#pragma unroll
      for (int j = 0; j < 8; ++j) acc[i][j] = fmaf(a4[i], b8[j], acc[i][j]);
  }
  // + b2
#pragma unroll
  for (int j = 0; j < 8; ++j) {
    float bv = b2s[8 * tx + j];
#pragma unroll
    for (int i = 0; i < 4; ++i) acc[i][j] += bv;
  }
  // cosine per edge pair: rows (4ty+2u, 4ty+2u+1) = edge e0+2ty+u
#pragma unroll
  for (int u = 0; u < 2; ++u) {
    float p11 = 0.f, p22 = 0.f, p12 = 0.f;
#pragma unroll
    for (int j = 0; j < 8; ++j) {
      float v1 = acc[2 * u][j], v2 = acc[2 * u + 1][j];
      p11 = fmaf(v1, v1, p11);
      p22 = fmaf(v2, v2, p22);
      p12 = fmaf(v1, v2, p12);
    }
    for (int off = 8; off > 0; off >>= 1) {
      p11 += __shfl_down(p11, off, 16);
      p22 += __shfl_down(p22, off, 16);
      p12 += __shfl_down(p12, off, 16);
    }
    if (tx == 0) {
      float n1 = fmaxf(sqrtf(p11), 1e-8f);
      float n2 = fmaxf(sqrtf(p22), 1e-8f);
      float cosv = p12 / (n1 * n2);
      ew_out[e0 + 2 * ty + u] = (cosv + 1.f) * 0.5f;
    }
  }
}

// ---------------------------------------------------------------------------
// K4/K5: degree scatter + deg->dinv (self-loop weight 1 folded in)
// ---------------------------------------------------------------------------
__global__ void deg_scatter(const int* __restrict__ col, const float* __restrict__ ew,
                            float* __restrict__ deg) {
  int e = blockIdx.x * 256 + threadIdx.x;
  if (e < NE) atomicAdd(&deg[col[e]], ew[e]);
}

__global__ void deg_to_dinv(float* __restrict__ deg) {
  int v = blockIdx.x * 256 + threadIdx.x;
  if (v < NN) deg[v] = rsqrtf(deg[v] + 1.0f);
}

// ---------------------------------------------------------------------------
// K6: feature GEMM [N,64]@[64,64] -> out (no bias). 64 nodes/block, 4x4 tiles.
// ---------------------------------------------------------------------------
__global__ __launch_bounds__(256) void gemm_feat(const float* __restrict__ in,
                                                 const float* __restrict__ W,
                                                 float* __restrict__ out, int n) {
  __shared__ __align__(16) float InT[64 * 68];
  __shared__ __align__(16) float Wl[64 * 64];
  int t = threadIdx.x;
  int v0 = blockIdx.x * 64;
  for (int i = t; i < 4096; i += 256) {
    Wl[i] = W[i];
    int v = i >> 6, k = i & 63;
    int vv = min(v0 + v, n - 1);
    InT[k * 68 + v] = in[vv * 64 + k];
  }
  __syncthreads();
  int tx = t & 15, ty = t >> 4;
  float acc[4][4];
#pragma unroll
  for (int i = 0; i < 4; ++i)
#pragma unroll
    for (int j = 0; j < 4; ++j) acc[i][j] = 0.f;
#pragma unroll 4
  for (int k = 0; k < 64; ++k) {
    float4 av = *(const float4*)&InT[k * 68 + 4 * ty];
    float4 bv = *(const float4*)&Wl[k * 64 + 4 * tx];
    float a4[4] = {av.x, av.y, av.z, av.w};
    float b4[4] = {bv.x, bv.y, bv.z, bv.w};
#pragma unroll
    for (int i = 0; i < 4; ++i)
#pragma unroll
      for (int j = 0; j < 4; ++j) acc[i][j] = fmaf(a4[i], b4[j], acc[i][j]);
  }
  for (int i = 0; i < 4; ++i) {
    int v = v0 + 4 * ty + i;
    if (v < n)
      *(float4*)&out[v * 64 + 4 * tx] =
          make_float4(acc[i][0], acc[i][1], acc[i][2], acc[i][3]);
  }
}

// ---------------------------------------------------------------------------
// K7: edge aggregation: out[col] += dinv[row]*ew*dinv[col] * xw[row]
// grid = NE*64/256 exactly.
// ---------------------------------------------------------------------------
__global__ void scatter_edges(const int* __restrict__ row, const int* __restrict__ col,
                              const float* __restrict__ ew, const float* __restrict__ dinv,
                              const float* __restrict__ xw, float* __restrict__ out) {
  int t = blockIdx.x * 256 + threadIdx.x;
  int e = t >> 6, c = t & 63;
  int r = row[e], cl = col[e];
  float nrm = dinv[r] * ew[e] * dinv[cl];
  atomicAdd(&out[cl * 64 + c], nrm * xw[r * 64 + c]);
}

// ---------------------------------------------------------------------------
// K8: add self-loop + bias + relu, in place on agg
// ---------------------------------------------------------------------------
__global__ void conv_finalize(float* __restrict__ agg, const float* __restrict__ xw,
                              const float* __restrict__ dinv, const float* __restrict__ bias) {
  int t = blockIdx.x * 256 + threadIdx.x;  // < NN*64
  int v = t >> 6, c = t & 63;
  float d = dinv[v];
  float val = agg[t] + d * d * xw[t] + bias[c];
  agg[t] = fmaxf(val, 0.f);
}

// ---------------------------------------------------------------------------
// K9: MLP head: relu(h@lin1+b) -> dropout(k_head) -> @lin2+b. 8 nodes/block.
// ---------------------------------------------------------------------------
__global__ __launch_bounds__(256) void head_kernel(const float* __restrict__ h,
                                                   const float* __restrict__ l1w,
                                                   const float* __restrict__ l1b,
                                                   const float* __restrict__ l2w,
                                                   const float* __restrict__ l2b,
                                                   float* __restrict__ out) {
  __shared__ float L1[2048];
  __shared__ float L1B[32];
  __shared__ float L2[320];
  __shared__ float L2B[10];
  __shared__ float hrow[8 * 64];
  __shared__ float M[8 * 33];
  int t = threadIdx.x;
  int v0 = blockIdx.x * 8;
  for (int i = t; i < 2048; i += 256) L1[i] = l1w[i];
  if (t < 32) L1B[t] = l1b[t];
  for (int i = t; i < 320; i += 256) L2[i] = l2w[i];
  if (t < 10) L2B[t] = l2b[t];
  for (int i = t; i < 512; i += 256) hrow[i] = h[v0 * 64 + i];

  uint32_t kp0, kp1, kh0, kh1;
  jax_split42(kp0, kp1, kh0, kh1);
  __syncthreads();

  int v = t >> 5, j = t & 31;
  float acc = L1B[j];
#pragma unroll
  for (int k = 0; k < 64; ++k) acc = fmaf(hrow[v * 64 + k], L1[k * 32 + j], acc);
  acc = fmaxf(acc, 0.f);
  uint32_t idx = (uint32_t)((v0 + v) * 32 + j);
#if JAX_PARTITIONABLE
  bool kp = bits_keep(tf_bits32(kh0, kh1, idx));
#else
  bool kp;
  {
    uint32_t o0, o1;
    if (idx < 1600000u) { threefry2x32(kh0, kh1, idx, idx + 1600000u, o0, o1); kp = bits_keep(o0); }
    else { threefry2x32(kh0, kh1, idx - 1600000u, idx, o0, o1); kp = bits_keep(o1); }
  }
#endif
  M[v * 33 + j] = kp ? acc * INV_KEEP : 0.f;
  __syncthreads();
  if (t < 80) {
    int vv = t / 10, f = t % 10;
    float s = L2B[f];
#pragma unroll
    for (int jj = 0; jj < 32; ++jj) s = fmaf(M[vv * 33 + jj], L2[jj * 10 + f], s);
    out[(v0 + vv) * 10 + f] = s;
  }
}

// ---------------------------------------------------------------------------
extern "C" void kernel_launch(void* const* d_in, const int* in_sizes, int n_in,
                              void* d_out, int out_size, void* d_ws, size_t ws_size,
                              hipStream_t stream) {
  const float* x       = (const float*)d_in[0];
  const int*   ei      = (const int*)d_in[1];
  const float* edgenet = (const float*)d_in[2];
  const float* pw1     = (const float*)d_in[3];
  const float* pb1     = (const float*)d_in[4];
  const float* pgamma  = (const float*)d_in[5];
  const float* pbeta   = (const float*)d_in[6];
  const float* pw2     = (const float*)d_in[7];
  const float* pb2     = (const float*)d_in[8];
  const float* c1w     = (const float*)d_in[9];
  const float* c1b     = (const float*)d_in[10];
  const float* c2w     = (const float*)d_in[11];
  const float* c2b     = (const float*)d_in[12];
  const float* l1w     = (const float*)d_in[13];
  const float* l1b     = (const float*)d_in[14];
  const float* l2w     = (const float*)d_in[15];
  const float* l2b     = (const float*)d_in[16];
  float* out = (float*)d_out;

  const int* rowp = ei;
  const int* colp = ei + NE;

  float* wsf     = (float*)d_ws;
  float* bn_sums = wsf;                 // 512
  float* bn_ab   = wsf + 512;           // 512
  float* EW      = wsf + 1024;          // NE
  float* DINV    = EW + NE;             // NN
  float* BUFA    = DINV + NN;           // NN*64
  float* BUFB    = BUFA + NN * 64;      // NN*64

  hipMemsetAsync(bn_sums, 0, 512 * sizeof(float), stream);
  bn_stats<<<2048, 256, 0, stream>>>(edgenet, pw1, pb1, bn_sums);
  bn_finalize<<<1, 256, 0, stream>>>(bn_sums, pgamma, pbeta, bn_ab);
  pae_edge<<<NE / 32, 256, 0, stream>>>(edgenet, pw1, pb1, bn_ab, pw2, pb2, EW);

  hipMemsetAsync(DINV, 0, NN * sizeof(float), stream);
  deg_scatter<<<(NE + 255) / 256, 256, 0, stream>>>(colp, EW, DINV);
  deg_to_dinv<<<(NN + 255) / 256, 256, 0, stream>>>(DINV);

  // conv1
  gemm_feat<<<(NN + 63) / 64, 256, 0, stream>>>(x, c1w, BUFA, NN);
  hipMemsetAsync(BUFB, 0, (size_t)NN * 64 * sizeof(float), stream);
  scatter_edges<<<NE * 64 / 256, 256, 0, stream>>>(rowp, colp, EW, DINV, BUFA, BUFB);
  conv_finalize<<<NN * 64 / 256, 256, 0, stream>>>(BUFB, BUFA, DINV, c1b);

  // conv2
  gemm_feat<<<(NN + 63) / 64, 256, 0, stream>>>(BUFB, c2w, BUFA, NN);
  hipMemsetAsync(BUFB, 0, (size_t)NN * 64 * sizeof(float), stream);
  scatter_edges<<<NE * 64 / 256, 256, 0, stream>>>(rowp, colp, EW, DINV, BUFA, BUFB);
  conv_finalize<<<NN * 64 / 256, 256, 0, stream>>>(BUFB, BUFA, DINV, c2b);

  // head
  head_kernel<<<NN / 8, 256, 0, stream>>>(BUFB, l1w, l1b, l2w, l2b, out);
}

// Round 2
// 1623.048 us; speedup vs baseline: 1.2153x; 1.2153x over previous
//
#include <hip/hip_runtime.h>
#include <stdint.h>

// ---------------------------------------------------------------------------
// Node_GCN: PAE edge weights (MLP+BN+dropout+cosine) -> 2x GCNConv -> MLP head
// R2: pae h@w2 GEMM moved to bf16 MFMA (16x16x32), threefry dropout kept exact
// fp32/int32; bn_stats rewritten as sync-free wave-uniform scalar-load version.
// Workspace layout (floats): [bn_sums 512][bn_ab 512][EW 1e6][DINV 1e5]
//                            [BUFA 6.4e6][BUFB 6.4e6]; W2T(bf16) overlaps BUFA.
// ---------------------------------------------------------------------------

#define NN 100000
#define NE 1000000
#define INV_KEEP (1.0f/0.7f)

typedef short bf16x8 __attribute__((ext_vector_type(8)));
typedef float f32x4  __attribute__((ext_vector_type(4)));

__device__ __forceinline__ uint32_t rotl32(uint32_t x, int r) {
  return (x << r) | (x >> (32 - r));
}

// Threefry-2x32, 20 rounds, exactly as in jax/_src/prng.py
__device__ __forceinline__ void threefry2x32(uint32_t k0, uint32_t k1,
                                             uint32_t x0, uint32_t x1,
                                             uint32_t& o0, uint32_t& o1) {
  uint32_t k2 = k0 ^ k1 ^ 0x1BD11BDAu;
  x0 += k0; x1 += k1;
#define TF_R(r) { x0 += x1; x1 = rotl32(x1, (r)); x1 ^= x0; }
  TF_R(13) TF_R(15) TF_R(26) TF_R(6)   x0 += k1; x1 += k2 + 1u;
  TF_R(17) TF_R(29) TF_R(16) TF_R(24)  x0 += k2; x1 += k0 + 2u;
  TF_R(13) TF_R(15) TF_R(26) TF_R(6)   x0 += k0; x1 += k1 + 3u;
  TF_R(17) TF_R(29) TF_R(16) TF_R(24)  x0 += k1; x1 += k2 + 4u;
  TF_R(13) TF_R(15) TF_R(26) TF_R(6)   x0 += k2; x1 += k0 + 5u;
#undef TF_R
  o0 = x0; o1 = x1;
}

// keys from jax.random.split(jax.random.key(42)), partitionable mode
__device__ __forceinline__ void jax_split42(uint32_t& kp0, uint32_t& kp1,
                                            uint32_t& kh0, uint32_t& kh1) {
  threefry2x32(0u, 42u, 0u, 0u, kp0, kp1);
  threefry2x32(0u, 42u, 0u, 1u, kh0, kh1);
}

__device__ __forceinline__ uint32_t tf_bits32(uint32_t k0, uint32_t k1, uint32_t idx) {
  uint32_t o0, o1;
  threefry2x32(k0, k1, 0u, idx, o0, o1);
  return o0 ^ o1;
}

// jax.random.uniform(bits) < 0.7  (keep probability)
__device__ __forceinline__ bool bits_keep(uint32_t bits) {
  float u = __uint_as_float((bits >> 9) | 0x3F800000u) - 1.0f;
  return u < 0.7f;
}

__device__ __forceinline__ uint16_t f2bf(float f) {
  uint32_t u = __float_as_uint(f);
  return (uint16_t)((u + 0x7FFFu + ((u >> 16) & 1u)) >> 16);
}

// ---------------------------------------------------------------------------
// K1: BN statistics, sync-free. Thread t -> (s=t>>7, c=t&127); edge data read
// via wave-uniform loads (scalar-promoted). 1000 blocks x 1000 edges.
// ---------------------------------------------------------------------------
__global__ __launch_bounds__(256) void bn_stats(const float* __restrict__ edgenet,
                                                const float* __restrict__ w1,
                                                const float* __restrict__ b1,
                                                float* __restrict__ sums) {
  int t = threadIdx.x;
  int c = t & 127, s = t >> 7;           // s is wave-uniform (waves 0,1 vs 2,3)
  float wA = w1[c], wB = w1[128 + c], bb = b1[c];
  const float2* ed2 = (const float2*)edgenet;
  int e0 = blockIdx.x * 1000;
  float sm0 = 0.f, sm1 = 0.f, q0 = 0.f, q1 = 0.f;
#pragma unroll 4
  for (int e = 0; e < 1000; e += 2) {
    float2 xa = ed2[(e0 + e) * 2 + s];
    float2 xb = ed2[(e0 + e + 1) * 2 + s];
    float h = fmaxf(fmaf(xa.y, wB, fmaf(xa.x, wA, bb)), 0.f);
    sm0 += h; q0 = fmaf(h, h, q0);
    h = fmaxf(fmaf(xb.y, wB, fmaf(xb.x, wA, bb)), 0.f);
    sm1 += h; q1 = fmaf(h, h, q1);
  }
  atomicAdd(&sums[t], sm0 + sm1);
  atomicAdd(&sums[256 + t], q0 + q1);
}

// ---------------------------------------------------------------------------
// K2: BN finalize -> affine (a,b): hn = h*a + b.   ab[0..255]=a, ab[256..511]=b
// ---------------------------------------------------------------------------
__global__ void bn_finalize(const float* __restrict__ sums,
                            const float* __restrict__ gamma,
                            const float* __restrict__ beta,
                            float* __restrict__ ab) {
  int t = threadIdx.x;  // 256
  int c = t & 127;
  const float invE = 1.0f / (float)NE;
  float mean = sums[t] * invE;
  float var = fmaxf(sums[256 + t] * invE - mean * mean, 0.f);
  float rstd = rsqrtf(var + 1e-5f);
  float a = gamma[c] * rstd;
  ab[t] = a;
  ab[256 + t] = beta[c] - mean * a;
}

// ---------------------------------------------------------------------------
// K2b: w2 -> bf16 transposed [n][k] for MFMA B-operand. 32 blocks x 256.
// ---------------------------------------------------------------------------
__global__ void w2_prep(const float* __restrict__ w2, uint32_t* __restrict__ w2t) {
  int i = blockIdx.x * 256 + threadIdx.x;  // < 8192, one uint = 2 bf16 along k
  int n = i >> 6, kp = i & 63;
  float f0 = w2[(2 * kp) * 128 + n];
  float f1 = w2[(2 * kp + 1) * 128 + n];
  w2t[i] = (uint32_t)f2bf(f0) | ((uint32_t)f2bf(f1) << 16);
}

// ---------------------------------------------------------------------------
// K3: PAE fused. 32 edges/block (64 rows), couts 128, K=128.
// Staging: h1=relu(x@w1+b1) -> BN affine -> exact threefry dropout -> bf16 into
// LDS hdt[row][k] (stride 136). w2t (bf16, [n][k]) staged to LDS. 4 waves, each
// one 16-row m-tile x 8 n-tiles via mfma_f32_16x16x32_bf16. Epilogue: cosine.
// MFMA layouts (m89/m120-verified): A m=lane&15,k=quad*8+j; B n=lane&15,
// k=quad*8+j; C/D col=lane&15,row=quad*4+reg.
// ---------------------------------------------------------------------------
__global__ __launch_bounds__(256) void pae_edge(const float* __restrict__ edgenet,
                                                const float* __restrict__ w1,
                                                const float* __restrict__ b1,
                                                const float* __restrict__ ab,
                                                const uint32_t* __restrict__ w2t,
                                                const float* __restrict__ b2,
                                                float* __restrict__ ew_out) {
  __shared__ __align__(16) uint16_t hdt[64 * 136];   // A tile, +8 bf16 pad
  __shared__ __align__(16) uint16_t w2s[128 * 136];  // B tile, +8 bf16 pad
  __shared__ float4 ed4[32];
  __shared__ float w1s[256], b1s[128], aS[256], bS[256], b2s[128];
  int t = threadIdx.x;
  int e0 = blockIdx.x * 32;
  if (t < 128) { w1s[t] = w1[t]; w1s[128 + t] = w1[128 + t]; b1s[t] = b1[t]; b2s[t] = b2[t]; }
  aS[t] = ab[t];
  bS[t] = ab[256 + t];
  if (t < 32) ed4[t] = ((const float4*)edgenet)[e0 + t];
  for (int i = t; i < 8192; i += 256) {            // stage w2t -> LDS
    int n = i >> 6, kp = i & 63;
    *(uint32_t*)&w2s[n * 136 + 2 * kp] = w2t[i];
  }
  uint32_t kp0, kp1, kh0, kh1;
  jax_split42(kp0, kp1, kh0, kh1);
  __syncthreads();

  // staging: dropout-applied normalized h1 -> bf16 -> hdt[2*el+s][c]
#pragma unroll 2
  for (int it = 0; it < 16; ++it) {
    int idx = it * 256 + t;        // [0, 4096)
    int el = idx & 31;             // edge within block
    int c = idx >> 5;              // channel [0,128)
    float4 xv = ed4[el];
    float wA = w1s[c], wB = w1s[128 + c], bb = b1s[c];
    float h0 = fmaxf(fmaf(xv.y, wB, fmaf(xv.x, wA, bb)), 0.f);   // s=0
    float h1 = fmaxf(fmaf(xv.w, wB, fmaf(xv.z, wA, bb)), 0.f);   // s=1
    float hn0 = fmaf(h0, aS[c], bS[c]);
    float hn1 = fmaf(h1, aS[128 + c], bS[128 + c]);
    uint32_t base = (uint32_t)((e0 + el) * 128 + c);
    bool keep0 = bits_keep(tf_bits32(kp0, kp1, base));
    bool keep1 = bits_keep(tf_bits32(kp0, kp1, base + 128000000u));
    float hd0 = keep0 ? hn0 * INV_KEEP : 0.f;
    float hd1 = keep1 ? hn1 * INV_KEEP : 0.f;
    hdt[(2 * el) * 136 + c]     = f2bf(hd0);
    hdt[(2 * el + 1) * 136 + c] = f2bf(hd1);
  }
  __syncthreads();

  int lane = t & 63, w = t >> 6;
  int cl = lane & 15, quad = lane >> 4;

  const uint16_t* arow = &hdt[(16 * w + cl) * 136];
  f32x4 acc[8];
#pragma unroll
  for (int nt = 0; nt < 8; ++nt) acc[nt] = (f32x4){0.f, 0.f, 0.f, 0.f};
  bf16x8 afr[4];
#pragma unroll
  for (int kt = 0; kt < 4; ++kt)
    afr[kt] = *(const bf16x8*)&arow[kt * 32 + quad * 8];
#pragma unroll
  for (int nt = 0; nt < 8; ++nt) {
    const uint16_t* brow = &w2s[(nt * 16 + cl) * 136];
#pragma unroll
    for (int kt = 0; kt < 4; ++kt) {
      bf16x8 bfr = *(const bf16x8*)&brow[kt * 32 + quad * 8];
      acc[nt] = __builtin_amdgcn_mfma_f32_16x16x32_bf16(afr[kt], bfr, acc[nt], 0, 0, 0);
    }
  }

  // epilogue: lane holds rows quad*4+{0..3} (2 edge pairs), col nt*16+cl
  float p11[2] = {0.f, 0.f}, p22[2] = {0.f, 0.f}, p12[2] = {0.f, 0.f};
#pragma unroll
  for (int nt = 0; nt < 8; ++nt) {
    float bv = b2s[nt * 16 + cl];
#pragma unroll
    for (int u = 0; u < 2; ++u) {
      float v1 = acc[nt][2 * u] + bv;
      float v2 = acc[nt][2 * u + 1] + bv;
      p11[u] = fmaf(v1, v1, p11[u]);
      p22[u] = fmaf(v2, v2, p22[u]);
      p12[u] = fmaf(v1, v2, p12[u]);
    }
  }
#pragma unroll
  for (int u = 0; u < 2; ++u) {
    float a = p11[u], b = p22[u], d = p12[u];
    for (int off = 1; off < 16; off <<= 1) {
      a += __shfl_xor(a, off, 64);
      b += __shfl_xor(b, off, 64);
      d += __shfl_xor(d, off, 64);
    }
    if (cl == 0) {
      float n1 = fmaxf(sqrtf(a), 1e-8f);
      float n2 = fmaxf(sqrtf(b), 1e-8f);
      ew_out[e0 + 8 * w + 2 * quad + u] = (d / (n1 * n2) + 1.f) * 0.5f;
    }
  }
}

// ---------------------------------------------------------------------------
// K4/K5: degree scatter + deg->dinv (self-loop weight 1 folded in)
// ---------------------------------------------------------------------------
__global__ void deg_scatter(const int* __restrict__ col, const float* __restrict__ ew,
                            float* __restrict__ deg) {
  int e = blockIdx.x * 256 + threadIdx.x;
  if (e < NE) atomicAdd(&deg[col[e]], ew[e]);
}

__global__ void deg_to_dinv(float* __restrict__ deg) {
  int v = blockIdx.x * 256 + threadIdx.x;
  if (v < NN) deg[v] = rsqrtf(deg[v] + 1.0f);
}

// ---------------------------------------------------------------------------
// K6: feature GEMM [N,64]@[64,64] -> out (no bias). 64 nodes/block, 4x4 tiles.
// ---------------------------------------------------------------------------
__global__ __launch_bounds__(256) void gemm_feat(const float* __restrict__ in,
                                                 const float* __restrict__ W,
                                                 float* __restrict__ out, int n) {
  __shared__ __align__(16) float InT[64 * 68];
  __shared__ __align__(16) float Wl[64 * 64];
  int t = threadIdx.x;
  int v0 = blockIdx.x * 64;
  for (int i = t; i < 4096; i += 256) {
    Wl[i] = W[i];
    int v = i >> 6, k = i & 63;
    int vv = min(v0 + v, n - 1);
    InT[k * 68 + v] = in[vv * 64 + k];
  }
  __syncthreads();
  int tx = t & 15, ty = t >> 4;
  float acc[4][4];
#pragma unroll
  for (int i = 0; i < 4; ++i)
#pragma unroll
    for (int j = 0; j < 4; ++j) acc[i][j] = 0.f;
#pragma unroll 4
  for (int k = 0; k < 64; ++k) {
    float4 av = *(const float4*)&InT[k * 68 + 4 * ty];
    float4 bv = *(const float4*)&Wl[k * 64 + 4 * tx];
    float a4[4] = {av.x, av.y, av.z, av.w};
    float b4[4] = {bv.x, bv.y, bv.z, bv.w};
#pragma unroll
    for (int i = 0; i < 4; ++i)
#pragma unroll
      for (int j = 0; j < 4; ++j) acc[i][j] = fmaf(a4[i], b4[j], acc[i][j]);
  }
  for (int i = 0; i < 4; ++i) {
    int v = v0 + 4 * ty + i;
    if (v < n)
      *(float4*)&out[v * 64 + 4 * tx] =
          make_float4(acc[i][0], acc[i][1], acc[i][2], acc[i][3]);
  }
}

// ---------------------------------------------------------------------------
// K7: edge aggregation: out[col] += dinv[row]*ew*dinv[col] * xw[row]
// ---------------------------------------------------------------------------
__global__ void scatter_edges(const int* __restrict__ row, const int* __restrict__ col,
                              const float* __restrict__ ew, const float* __restrict__ dinv,
                              const float* __restrict__ xw, float* __restrict__ out) {
  int t = blockIdx.x * 256 + threadIdx.x;
  int e = t >> 6, c = t & 63;
  int r = row[e], cl = col[e];
  float nrm = dinv[r] * ew[e] * dinv[cl];
  atomicAdd(&out[cl * 64 + c], nrm * xw[r * 64 + c]);
}

// ---------------------------------------------------------------------------
// K8: add self-loop + bias + relu, in place on agg
// ---------------------------------------------------------------------------
__global__ void conv_finalize(float* __restrict__ agg, const float* __restrict__ xw,
                              const float* __restrict__ dinv, const float* __restrict__ bias) {
  int t = blockIdx.x * 256 + threadIdx.x;  // < NN*64
  int v = t >> 6, c = t & 63;
  float d = dinv[v];
  float val = agg[t] + d * d * xw[t] + bias[c];
  agg[t] = fmaxf(val, 0.f);
}

// ---------------------------------------------------------------------------
// K9: MLP head: relu(h@lin1+b) -> dropout(k_head) -> @lin2+b. 8 nodes/block.
// ---------------------------------------------------------------------------
__global__ __launch_bounds__(256) void head_kernel(const float* __restrict__ h,
                                                   const float* __restrict__ l1w,
                                                   const float* __restrict__ l1b,
                                                   const float* __restrict__ l2w,
                                                   const float* __restrict__ l2b,
                                                   float* __restrict__ out) {
  __shared__ float L1[2048];
  __shared__ float L1B[32];
  __shared__ float L2[320];
  __shared__ float L2B[10];
  __shared__ float hrow[8 * 64];
  __shared__ float M[8 * 33];
  int t = threadIdx.x;
  int v0 = blockIdx.x * 8;
  for (int i = t; i < 2048; i += 256) L1[i] = l1w[i];
  if (t < 32) L1B[t] = l1b[t];
  for (int i = t; i < 320; i += 256) L2[i] = l2w[i];
  if (t < 10) L2B[t] = l2b[t];
  for (int i = t; i < 512; i += 256) hrow[i] = h[v0 * 64 + i];

  uint32_t kp0, kp1, kh0, kh1;
  jax_split42(kp0, kp1, kh0, kh1);
  __syncthreads();

  int v = t >> 5, j = t & 31;
  float acc = L1B[j];
#pragma unroll
  for (int k = 0; k < 64; ++k) acc = fmaf(hrow[v * 64 + k], L1[k * 32 + j], acc);
  acc = fmaxf(acc, 0.f);
  uint32_t idx = (uint32_t)((v0 + v) * 32 + j);
  bool kp = bits_keep(tf_bits32(kh0, kh1, idx));
  M[v * 33 + j] = kp ? acc * INV_KEEP : 0.f;
  __syncthreads();
  if (t < 80) {
    int vv = t / 10, f = t % 10;
    float s = L2B[f];
#pragma unroll
    for (int jj = 0; jj < 32; ++jj) s = fmaf(M[vv * 33 + jj], L2[jj * 10 + f], s);
    out[(v0 + vv) * 10 + f] = s;
  }
}

// ---------------------------------------------------------------------------
extern "C" void kernel_launch(void* const* d_in, const int* in_sizes, int n_in,
                              void* d_out, int out_size, void* d_ws, size_t ws_size,
                              hipStream_t stream) {
  const float* x       = (const float*)d_in[0];
  const int*   ei      = (const int*)d_in[1];
  const float* edgenet = (const float*)d_in[2];
  const float* pw1     = (const float*)d_in[3];
  const float* pb1     = (const float*)d_in[4];
  const float* pgamma  = (const float*)d_in[5];
  const float* pbeta   = (const float*)d_in[6];
  const float* pw2     = (const float*)d_in[7];
  const float* pb2     = (const float*)d_in[8];
  const float* c1w     = (const float*)d_in[9];
  const float* c1b     = (const float*)d_in[10];
  const float* c2w     = (const float*)d_in[11];
  const float* c2b     = (const float*)d_in[12];
  const float* l1w     = (const float*)d_in[13];
  const float* l1b     = (const float*)d_in[14];
  const float* l2w     = (const float*)d_in[15];
  const float* l2b     = (const float*)d_in[16];
  float* out = (float*)d_out;

  const int* rowp = ei;
  const int* colp = ei + NE;

  float* wsf     = (float*)d_ws;
  float* bn_sums = wsf;                 // 512
  float* bn_ab   = wsf + 512;           // 512
  float* EW      = wsf + 1024;          // NE
  float* DINV    = EW + NE;             // NN
  float* BUFA    = DINV + NN;           // NN*64
  float* BUFB    = BUFA + NN * 64;      // NN*64
  uint32_t* W2T  = (uint32_t*)BUFA;     // 8192 u32, overlaps BUFA (free until conv1)

  hipMemsetAsync(bn_sums, 0, 512 * sizeof(float), stream);
  bn_stats<<<1000, 256, 0, stream>>>(edgenet, pw1, pb1, bn_sums);
  bn_finalize<<<1, 256, 0, stream>>>(bn_sums, pgamma, pbeta, bn_ab);
  w2_prep<<<32, 256, 0, stream>>>(pw2, W2T);
  pae_edge<<<NE / 32, 256, 0, stream>>>(edgenet, pw1, pb1, bn_ab, W2T, pb2, EW);

  hipMemsetAsync(DINV, 0, NN * sizeof(float), stream);
  deg_scatter<<<(NE + 255) / 256, 256, 0, stream>>>(colp, EW, DINV);
  deg_to_dinv<<<(NN + 255) / 256, 256, 0, stream>>>(DINV);

  // conv1
  gemm_feat<<<(NN + 63) / 64, 256, 0, stream>>>(x, c1w, BUFA, NN);
  hipMemsetAsync(BUFB, 0, (size_t)NN * 64 * sizeof(float), stream);
  scatter_edges<<<NE * 64 / 256, 256, 0, stream>>>(rowp, colp, EW, DINV, BUFA, BUFB);
  conv_finalize<<<NN * 64 / 256, 256, 0, stream>>>(BUFB, BUFA, DINV, c1b);

  // conv2
  gemm_feat<<<(NN + 63) / 64, 256, 0, stream>>>(BUFB, c2w, BUFA, NN);
  hipMemsetAsync(BUFB, 0, (size_t)NN * 64 * sizeof(float), stream);
  scatter_edges<<<NE * 64 / 256, 256, 0, stream>>>(rowp, colp, EW, DINV, BUFA, BUFB);
  conv_finalize<<<NN * 64 / 256, 256, 0, stream>>>(BUFB, BUFA, DINV, c2b);

  // head
  head_kernel<<<NN / 8, 256, 0, stream>>>(BUFB, l1w, l1b, l2w, l2b, out);
}

// Round 3
// 1371.415 us; speedup vs baseline: 1.4383x; 1.1835x over previous
//
#include <hip/hip_runtime.h>
#include <stdint.h>

// ---------------------------------------------------------------------------
// Node_GCN: PAE edge weights (MLP+BN+dropout+cosine) -> 2x GCNConv -> MLP head
// R3: pae_edge computes dropout-applied hidden directly in MFMA A-fragment
// layout (no A-side LDS staging), constexpr threefry keys, integer keep test,
// INV_KEEP folded into BN affine, deg_scatter fused into pae epilogue.
// Workspace (floats): [bn_sums 512][pad 512][EW 1e6][DINV 1e5][BUFA][BUFB]
// W2T(bf16) overlaps BUFA head; PRM(896f) overlaps BUFB head (both dead by
// the time conv1 overwrites them; stream-ordered).
// ---------------------------------------------------------------------------

#define NN 100000
#define NE 1000000
#define INV_KEEP (1.0f/0.7f)
// uniform(bits) < 0.7  <=>  bits < 5872026<<9   (0.7f = 0x3F333333 exactly)
#define KEEP_THR 3006477312u

typedef short bf16x8 __attribute__((ext_vector_type(8)));
typedef float f32x4  __attribute__((ext_vector_type(4)));
typedef uint32_t u32x4 __attribute__((ext_vector_type(4)));

// ---- threefry2x32 (20 rounds), exact jax/_src/prng.py semantics -----------
__host__ __device__ constexpr uint32_t rotl32c(uint32_t x, int r) {
  return (x << r) | (x >> (32 - r));
}

struct TFK { uint32_t a, b; };
__host__ __device__ constexpr TFK tf_const(uint32_t k0, uint32_t k1,
                                           uint32_t x0, uint32_t x1) {
  uint32_t k2 = k0 ^ k1 ^ 0x1BD11BDAu;
  x0 += k0; x1 += k1;
#define TFC_R(r) { x0 += x1; x1 = rotl32c(x1, (r)); x1 ^= x0; }
  TFC_R(13) TFC_R(15) TFC_R(26) TFC_R(6)   x0 += k1; x1 += k2 + 1u;
  TFC_R(17) TFC_R(29) TFC_R(16) TFC_R(24)  x0 += k2; x1 += k0 + 2u;
  TFC_R(13) TFC_R(15) TFC_R(26) TFC_R(6)   x0 += k0; x1 += k1 + 3u;
  TFC_R(17) TFC_R(29) TFC_R(16) TFC_R(24)  x0 += k1; x1 += k2 + 4u;
  TFC_R(13) TFC_R(15) TFC_R(26) TFC_R(6)   x0 += k2; x1 += k0 + 5u;
#undef TFC_R
  return TFK{x0, x1};
}

// keys from jax.random.split(jax.random.key(42)), partitionable mode
constexpr TFK KP = tf_const(0u, 42u, 0u, 0u);
constexpr TFK KH = tf_const(0u, 42u, 0u, 1u);

// partitionable random bits for element idx: threefry(key,(0,idx)) -> o0^o1
template <uint32_t K0, uint32_t K1>
__device__ __forceinline__ uint32_t tf_bits(uint32_t idx) {
  constexpr uint32_t K2 = K0 ^ K1 ^ 0x1BD11BDAu;
  uint32_t x0 = K0;
  uint32_t x1 = idx + K1;
#define TF_R(r) { x0 += x1; x1 = rotl32c(x1, (r)); x1 ^= x0; }
  TF_R(13) TF_R(15) TF_R(26) TF_R(6)   x0 += K1; x1 += K2 + 1u;
  TF_R(17) TF_R(29) TF_R(16) TF_R(24)  x0 += K2; x1 += K0 + 2u;
  TF_R(13) TF_R(15) TF_R(26) TF_R(6)   x0 += K0; x1 += K1 + 3u;
  TF_R(17) TF_R(29) TF_R(16) TF_R(24)  x0 += K1; x1 += K2 + 4u;
  TF_R(13) TF_R(15) TF_R(26) TF_R(6)   x0 += K2; x1 += K0 + 5u;
#undef TF_R
  return x0 ^ x1;
}

__device__ __forceinline__ uint16_t f2bf(float f) {  // RNE (cold paths only)
  uint32_t u = __float_as_uint(f);
  return (uint16_t)((u + 0x7FFFu + ((u >> 16) & 1u)) >> 16);
}

// ---------------------------------------------------------------------------
// K1: BN statistics, sync-free wave-uniform loads. 1000 blocks x 1000 edges.
// ---------------------------------------------------------------------------
__global__ __launch_bounds__(256) void bn_stats(const float* __restrict__ edgenet,
                                                const float* __restrict__ w1,
                                                const float* __restrict__ b1,
                                                float* __restrict__ sums) {
  int t = threadIdx.x;
  int c = t & 127, s = t >> 7;
  float wA = w1[c], wB = w1[128 + c], bb = b1[c];
  const float2* ed2 = (const float2*)edgenet;
  int e0 = blockIdx.x * 1000;
  float sm0 = 0.f, sm1 = 0.f, q0 = 0.f, q1 = 0.f;
#pragma unroll 4
  for (int e = 0; e < 1000; e += 2) {
    float2 xa = ed2[(e0 + e) * 2 + s];
    float2 xb = ed2[(e0 + e + 1) * 2 + s];
    float h = fmaxf(fmaf(xa.y, wB, fmaf(xa.x, wA, bb)), 0.f);
    sm0 += h; q0 = fmaf(h, h, q0);
    h = fmaxf(fmaf(xb.y, wB, fmaf(xb.x, wA, bb)), 0.f);
    sm1 += h; q1 = fmaf(h, h, q1);
  }
  atomicAdd(&sums[t], sm0 + sm1);
  atomicAdd(&sums[256 + t], q0 + q1);
}

// ---------------------------------------------------------------------------
// K2: finalize -> packed param table PRM (896 floats):
//   [0]wA[128] [128]wB[128] [256]b1[128] [384]aK[256] [640]bK[256]
// where aK/bK are the BN affine with INV_KEEP folded in (per half s).
// ---------------------------------------------------------------------------
__global__ void bn_finalize(const float* __restrict__ sums,
                            const float* __restrict__ w1,
                            const float* __restrict__ b1,
                            const float* __restrict__ gamma,
                            const float* __restrict__ beta,
                            float* __restrict__ prm) {
  int t = threadIdx.x;  // 256
  int c = t & 127;
  const float invE = 1.0f / (float)NE;
  float mean = sums[t] * invE;
  float var = fmaxf(sums[256 + t] * invE - mean * mean, 0.f);
  float rstd = rsqrtf(var + 1e-5f);
  float a = gamma[c] * rstd;
  prm[384 + t] = a * INV_KEEP;
  prm[640 + t] = (beta[c] - mean * a) * INV_KEEP;
  if (t < 128) { prm[t] = w1[t]; prm[128 + t] = w1[128 + t]; prm[256 + t] = b1[t]; }
}

// ---------------------------------------------------------------------------
// K2b: w2 -> bf16 transposed [n][k] for MFMA B-operand.
// ---------------------------------------------------------------------------
__global__ void w2_prep(const float* __restrict__ w2, uint32_t* __restrict__ w2t) {
  int i = blockIdx.x * 256 + threadIdx.x;  // < 8192, one uint = 2 bf16 along k
  int n = i >> 6, kp = i & 63;
  float f0 = w2[(2 * kp) * 128 + n];
  float f1 = w2[(2 * kp + 1) * 128 + n];
  w2t[i] = (uint32_t)f2bf(f0) | ((uint32_t)f2bf(f1) << 16);
}

// ---------------------------------------------------------------------------
// K3: PAE fused, fragment-direct. 32 edges/block (64 rows), 4 waves.
// Wave w owns m-tile rows 16w..16w+15. Lane (cl,quad): row=16w+cl,
// channels c = kt*32+quad*8+j computed straight into the A fragment
// (A: m=lane&15, k=quad*8+j — m89-verified). B (w2t bf16 [n][k]) staged in
// LDS. Epilogue: cosine + fused degree atomicAdd.
// ---------------------------------------------------------------------------
__global__ __launch_bounds__(256) void pae_edge(const float* __restrict__ edgenet,
                                                const float* __restrict__ prm_g,
                                                const uint32_t* __restrict__ w2t,
                                                const float* __restrict__ b2,
                                                const int* __restrict__ colp,
                                                float* __restrict__ ew_out,
                                                float* __restrict__ deg) {
  __shared__ __align__(16) uint16_t w2s[128 * 136];  // B tile [n][k], +8 pad
  __shared__ __align__(16) float prm[896];
  __shared__ float b2s[128];
  int t = threadIdx.x;
  int e0 = blockIdx.x * 32;
  for (int i = t; i < 8192; i += 256) {               // stage w2t -> LDS
    int n = i >> 6, kp = i & 63;
    *(uint32_t*)&w2s[n * 136 + 2 * kp] = w2t[i];
  }
  for (int i = t; i < 896; i += 256) prm[i] = prm_g[i];
  if (t < 128) b2s[t] = b2[t];
  __syncthreads();

  int lane = t & 63, w = t >> 6;
  int cl = lane & 15, quad = lane >> 4;
  int quad8 = quad * 8;
  int row = 16 * w + cl;
  int el = row >> 1, s = row & 1;
  int so = s << 7;                                    // s*128
  float2 xv = *(const float2*)&edgenet[(size_t)(e0 + el) * 4 + 2 * s];
  uint32_t rowbase = (uint32_t)(e0 + el) * 128u + (s ? 128000000u : 0u);

  f32x4 acc[8];
#pragma unroll
  for (int nt = 0; nt < 8; ++nt) acc[nt] = (f32x4){0.f, 0.f, 0.f, 0.f};

#pragma unroll 1
  for (int kt = 0; kt < 4; ++kt) {
    int c0 = kt * 32 + quad8;
    float wa[8], wb[8], bb[8], ak[8], bk[8];
    *(float4*)&wa[0] = *(const float4*)&prm[c0];
    *(float4*)&wa[4] = *(const float4*)&prm[c0 + 4];
    *(float4*)&wb[0] = *(const float4*)&prm[128 + c0];
    *(float4*)&wb[4] = *(const float4*)&prm[132 + c0];
    *(float4*)&bb[0] = *(const float4*)&prm[256 + c0];
    *(float4*)&bb[4] = *(const float4*)&prm[260 + c0];
    *(float4*)&ak[0] = *(const float4*)&prm[384 + so + c0];
    *(float4*)&ak[4] = *(const float4*)&prm[388 + so + c0];
    *(float4*)&bk[0] = *(const float4*)&prm[640 + so + c0];
    *(float4*)&bk[4] = *(const float4*)&prm[644 + so + c0];
    uint32_t pk[4];
#pragma unroll
    for (int jp = 0; jp < 4; ++jp) {
      float hd[2];
#pragma unroll
      for (int q = 0; q < 2; ++q) {
        int j = 2 * jp + q;
        float h = fmaxf(fmaf(xv.y, wb[j], fmaf(xv.x, wa[j], bb[j])), 0.f);
        float hn = fmaf(h, ak[j], bk[j]);
        uint32_t bits = tf_bits<KP.a, KP.b>(rowbase + (uint32_t)(c0 + j));
        hd[q] = (bits < KEEP_THR) ? hn : 0.f;
      }
      pk[jp] = ((__float_as_uint(hd[0]) + 0x8000u) >> 16) |
               ((__float_as_uint(hd[1]) + 0x8000u) & 0xFFFF0000u);
    }
    u32x4 pkv = {pk[0], pk[1], pk[2], pk[3]};
    bf16x8 afr = __builtin_bit_cast(bf16x8, pkv);
    const uint16_t* bbase = &w2s[(size_t)c0];
#pragma unroll
    for (int nt = 0; nt < 8; ++nt) {
      bf16x8 bfr = *(const bf16x8*)&bbase[(nt * 16 + cl) * 136];
      acc[nt] = __builtin_amdgcn_mfma_f32_16x16x32_bf16(afr, bfr, acc[nt], 0, 0, 0);
    }
  }

  // epilogue: lane holds C rows quad*4+{0..3} (edge pairs), col nt*16+cl
  float p11[2] = {0.f, 0.f}, p22[2] = {0.f, 0.f}, p12[2] = {0.f, 0.f};
#pragma unroll
  for (int nt = 0; nt < 8; ++nt) {
    float bv = b2s[nt * 16 + cl];
#pragma unroll
    for (int u = 0; u < 2; ++u) {
      float v1 = acc[nt][2 * u] + bv;
      float v2 = acc[nt][2 * u + 1] + bv;
      p11[u] = fmaf(v1, v1, p11[u]);
      p22[u] = fmaf(v2, v2, p22[u]);
      p12[u] = fmaf(v1, v2, p12[u]);
    }
  }
#pragma unroll
  for (int u = 0; u < 2; ++u) {
    float a = p11[u], b = p22[u], d = p12[u];
    for (int off = 1; off < 16; off <<= 1) {
      a += __shfl_xor(a, off, 64);
      b += __shfl_xor(b, off, 64);
      d += __shfl_xor(d, off, 64);
    }
    if (cl == 0) {
      int e = e0 + 8 * w + 2 * quad + u;
      float n1 = fmaxf(sqrtf(a), 1e-8f);
      float n2 = fmaxf(sqrtf(b), 1e-8f);
      float ew = (d / (n1 * n2) + 1.f) * 0.5f;
      ew_out[e] = ew;
      atomicAdd(&deg[colp[e]], ew);   // fused degree scatter
    }
  }
}

// ---------------------------------------------------------------------------
// K5: deg -> dinv (self-loop weight 1 folded in)
// ---------------------------------------------------------------------------
__global__ void deg_to_dinv(float* __restrict__ deg) {
  int v = blockIdx.x * 256 + threadIdx.x;
  if (v < NN) deg[v] = rsqrtf(deg[v] + 1.0f);
}

// ---------------------------------------------------------------------------
// K6: feature GEMM [N,64]@[64,64] -> out (no bias). 64 nodes/block, 4x4 tiles.
// ---------------------------------------------------------------------------
__global__ __launch_bounds__(256) void gemm_feat(const float* __restrict__ in,
                                                 const float* __restrict__ W,
                                                 float* __restrict__ out, int n) {
  __shared__ __align__(16) float InT[64 * 68];
  __shared__ __align__(16) float Wl[64 * 64];
  int t = threadIdx.x;
  int v0 = blockIdx.x * 64;
  for (int i = t; i < 4096; i += 256) {
    Wl[i] = W[i];
    int v = i >> 6, k = i & 63;
    int vv = min(v0 + v, n - 1);
    InT[k * 68 + v] = in[vv * 64 + k];
  }
  __syncthreads();
  int tx = t & 15, ty = t >> 4;
  float acc[4][4];
#pragma unroll
  for (int i = 0; i < 4; ++i)
#pragma unroll
    for (int j = 0; j < 4; ++j) acc[i][j] = 0.f;
#pragma unroll 4
  for (int k = 0; k < 64; ++k) {
    float4 av = *(const float4*)&InT[k * 68 + 4 * ty];
    float4 bv = *(const float4*)&Wl[k * 64 + 4 * tx];
    float a4[4] = {av.x, av.y, av.z, av.w};
    float b4[4] = {bv.x, bv.y, bv.z, bv.w};
#pragma unroll
    for (int i = 0; i < 4; ++i)
#pragma unroll
      for (int j = 0; j < 4; ++j) acc[i][j] = fmaf(a4[i], b4[j], acc[i][j]);
  }
  for (int i = 0; i < 4; ++i) {
    int v = v0 + 4 * ty + i;
    if (v < n)
      *(float4*)&out[v * 64 + 4 * tx] =
          make_float4(acc[i][0], acc[i][1], acc[i][2], acc[i][3]);
  }
}

// ---------------------------------------------------------------------------
// K7: edge aggregation: out[col] += dinv[row]*ew*dinv[col] * xw[row]
// ---------------------------------------------------------------------------
__global__ void scatter_edges(const int* __restrict__ row, const int* __restrict__ col,
                              const float* __restrict__ ew, const float* __restrict__ dinv,
                              const float* __restrict__ xw, float* __restrict__ out) {
  int t = blockIdx.x * 256 + threadIdx.x;
  int e = t >> 6, c = t & 63;
  int r = row[e], cl = col[e];
  float nrm = dinv[r] * ew[e] * dinv[cl];
  atomicAdd(&out[cl * 64 + c], nrm * xw[r * 64 + c]);
}

// ---------------------------------------------------------------------------
// K8: add self-loop + bias + relu, in place on agg
// ---------------------------------------------------------------------------
__global__ void conv_finalize(float* __restrict__ agg, const float* __restrict__ xw,
                              const float* __restrict__ dinv, const float* __restrict__ bias) {
  int t = blockIdx.x * 256 + threadIdx.x;  // < NN*64
  int v = t >> 6, c = t & 63;
  float d = dinv[v];
  float val = agg[t] + d * d * xw[t] + bias[c];
  agg[t] = fmaxf(val, 0.f);
}

// ---------------------------------------------------------------------------
// K9: MLP head: relu(h@lin1+b) -> dropout(k_head) -> @lin2+b. 8 nodes/block.
// ---------------------------------------------------------------------------
__global__ __launch_bounds__(256) void head_kernel(const float* __restrict__ h,
                                                   const float* __restrict__ l1w,
                                                   const float* __restrict__ l1b,
                                                   const float* __restrict__ l2w,
                                                   const float* __restrict__ l2b,
                                                   float* __restrict__ out) {
  __shared__ float L1[2048];
  __shared__ float L1B[32];
  __shared__ float L2[320];
  __shared__ float L2B[10];
  __shared__ float hrow[8 * 64];
  __shared__ float M[8 * 33];
  int t = threadIdx.x;
  int v0 = blockIdx.x * 8;
  for (int i = t; i < 2048; i += 256) L1[i] = l1w[i];
  if (t < 32) L1B[t] = l1b[t];
  for (int i = t; i < 320; i += 256) L2[i] = l2w[i];
  if (t < 10) L2B[t] = l2b[t];
  for (int i = t; i < 512; i += 256) hrow[i] = h[v0 * 64 + i];
  __syncthreads();

  int v = t >> 5, j = t & 31;
  float acc = L1B[j];
#pragma unroll
  for (int k = 0; k < 64; ++k) acc = fmaf(hrow[v * 64 + k], L1[k * 32 + j], acc);
  acc = fmaxf(acc, 0.f);
  uint32_t idx = (uint32_t)((v0 + v) * 32 + j);
  bool kp = tf_bits<KH.a, KH.b>(idx) < KEEP_THR;
  M[v * 33 + j] = kp ? acc * INV_KEEP : 0.f;
  __syncthreads();
  if (t < 80) {
    int vv = t / 10, f = t % 10;
    float s = L2B[f];
#pragma unroll
    for (int jj = 0; jj < 32; ++jj) s = fmaf(M[vv * 33 + jj], L2[jj * 10 + f], s);
    out[(v0 + vv) * 10 + f] = s;
  }
}

// ---------------------------------------------------------------------------
extern "C" void kernel_launch(void* const* d_in, const int* in_sizes, int n_in,
                              void* d_out, int out_size, void* d_ws, size_t ws_size,
                              hipStream_t stream) {
  const float* x       = (const float*)d_in[0];
  const int*   ei      = (const int*)d_in[1];
  const float* edgenet = (const float*)d_in[2];
  const float* pw1     = (const float*)d_in[3];
  const float* pb1     = (const float*)d_in[4];
  const float* pgamma  = (const float*)d_in[5];
  const float* pbeta   = (const float*)d_in[6];
  const float* pw2     = (const float*)d_in[7];
  const float* pb2     = (const float*)d_in[8];
  const float* c1w     = (const float*)d_in[9];
  const float* c1b     = (const float*)d_in[10];
  const float* c2w     = (const float*)d_in[11];
  const float* c2b     = (const float*)d_in[12];
  const float* l1w     = (const float*)d_in[13];
  const float* l1b     = (const float*)d_in[14];
  const float* l2w     = (const float*)d_in[15];
  const float* l2b     = (const float*)d_in[16];
  float* out = (float*)d_out;

  const int* rowp = ei;
  const int* colp = ei + NE;

  float* wsf     = (float*)d_ws;
  float* bn_sums = wsf;                 // 512
  float* EW      = wsf + 1024;          // NE
  float* DINV    = EW + NE;             // NN
  float* BUFA    = DINV + NN;           // NN*64
  float* BUFB    = BUFA + NN * 64;      // NN*64
  uint32_t* W2T  = (uint32_t*)BUFA;     // 8192 u32 (dead before conv1 gemm)
  float* PRM     = BUFB;                // 896 floats (dead before conv1 memset)

  hipMemsetAsync(bn_sums, 0, 512 * sizeof(float), stream);
  hipMemsetAsync(DINV, 0, NN * sizeof(float), stream);
  bn_stats<<<1000, 256, 0, stream>>>(edgenet, pw1, pb1, bn_sums);
  bn_finalize<<<1, 256, 0, stream>>>(bn_sums, pw1, pb1, pgamma, pbeta, PRM);
  w2_prep<<<32, 256, 0, stream>>>(pw2, W2T);
  pae_edge<<<NE / 32, 256, 0, stream>>>(edgenet, PRM, W2T, pb2, colp, EW, DINV);
  deg_to_dinv<<<(NN + 255) / 256, 256, 0, stream>>>(DINV);

  // conv1
  gemm_feat<<<(NN + 63) / 64, 256, 0, stream>>>(x, c1w, BUFA, NN);
  hipMemsetAsync(BUFB, 0, (size_t)NN * 64 * sizeof(float), stream);
  scatter_edges<<<NE * 64 / 256, 256, 0, stream>>>(rowp, colp, EW, DINV, BUFA, BUFB);
  conv_finalize<<<NN * 64 / 256, 256, 0, stream>>>(BUFB, BUFA, DINV, c1b);

  // conv2
  gemm_feat<<<(NN + 63) / 64, 256, 0, stream>>>(BUFB, c2w, BUFA, NN);
  hipMemsetAsync(BUFB, 0, (size_t)NN * 64 * sizeof(float), stream);
  scatter_edges<<<NE * 64 / 256, 256, 0, stream>>>(rowp, colp, EW, DINV, BUFA, BUFB);
  conv_finalize<<<NN * 64 / 256, 256, 0, stream>>>(BUFB, BUFA, DINV, c2b);

  // head
  head_kernel<<<NN / 8, 256, 0, stream>>>(BUFB, l1w, l1b, l2w, l2b, out);
}